// Round 1
// baseline (104.820 us; speedup 1.0000x reference)
//
#include <hip/hip_runtime.h>

// Box-log-edge kernel: reference does 4 VALID 11x11 box-half convs on a
// reflect-padded +0.01 image, then log-ratios + L2 norm.
// Strategy: LDS tile + separable column sums (top6/bot6/full11), sliding
// horizontal window, float4 stores.

#define KR 5
#define TW 64            // output tile width
#define TH 32            // output tile height
#define PW (TW + 2*KR)   // 74 padded cols
#define PH (TH + 2*KR)   // 42 padded rows
#define LSTRIDE 75       // LDS row stride (pad to break pow2 conflicts)
#define N 512

__global__ __launch_bounds__(256) void boxlog_kernel(
    const float* __restrict__ x, float* __restrict__ out)
{
    __shared__ float tile[PH][LSTRIDE];
    __shared__ float top6[TH][LSTRIDE];
    __shared__ float bot6[TH][LSTRIDE];
    __shared__ float full11[TH][LSTRIDE];

    const int tid = threadIdx.x;
    const int X0 = blockIdx.x * TW;
    const int Y0 = blockIdx.y * TH;
    const float* xb = x + (size_t)blockIdx.z * N * N;
    float* outb = out + (size_t)blockIdx.z * N * N;

    // Phase 0: load reflect-padded tile, +0.01 shift
    for (int e = tid; e < PH * PW; e += 256) {
        int r = e / PW, c = e - r * PW;
        int iy = Y0 + r - KR;
        iy = iy < 0 ? -iy : (iy > N-1 ? 2*(N-1) - iy : iy);
        int ix = X0 + c - KR;
        ix = ix < 0 ? -ix : (ix > N-1 ? 2*(N-1) - ix : ix);
        tile[r][c] = xb[iy * N + ix] + 0.01f;
    }
    __syncthreads();

    // Phase A: vertical sums per (output row, padded col):
    // top6 = rows r..r+5, bot6 = rows r+5..r+10, full11 = rows r..r+10
    for (int e = tid; e < TH * PW; e += 256) {
        int r = e / PW, c = e - r * PW;
        float t0 = tile[r+0][c], t1 = tile[r+1][c], t2 = tile[r+2][c];
        float t3 = tile[r+3][c], t4 = tile[r+4][c], t5 = tile[r+5][c];
        float t6 = tile[r+6][c], t7 = tile[r+7][c], t8 = tile[r+8][c];
        float t9 = tile[r+9][c], t10 = tile[r+10][c];
        float tp = ((t0+t1)+(t2+t3))+(t4+t5);
        float bt = ((t5+t6)+(t7+t8))+(t9+t10);
        top6[r][c] = tp;
        bot6[r][c] = bt;
        full11[r][c] = tp + bt - t5;
    }
    __syncthreads();

    // Phase B: each thread computes a 4-wide strip on 2 rows, sliding window
    const int tx = tid & 15;   // 16 strips of 4 -> 64 cols
    const int ty = tid >> 4;   // 16 -> 2 rows each -> 32 rows
    const int x0 = tx * 4;

    #pragma unroll
    for (int ry = 0; ry < 2; ++ry) {
        const int yr = ty * 2 + ry;
        float gx1 = 0.f, gx2 = 0.f, gy1 = 0.f, gy2 = 0.f;
        #pragma unroll
        for (int dx = 0; dx <= 5; ++dx)  gx1 += full11[yr][x0 + dx];
        #pragma unroll
        for (int dx = 5; dx <= 10; ++dx) gx2 += full11[yr][x0 + dx];
        #pragma unroll
        for (int dx = 0; dx <= 10; ++dx) {
            gy1 += top6[yr][x0 + dx];
            gy2 += bot6[yr][x0 + dx];
        }
        float4 res;
        {
            float lx = __logf(gx1) - __logf(gx2);
            float ly = __logf(gy1) - __logf(gy2);
            res.x = sqrtf(lx * lx + ly * ly);
        }
        #pragma unroll
        for (int p = 1; p < 4; ++p) {
            gx1 += full11[yr][x0 + p + 5]  - full11[yr][x0 + p - 1];
            gx2 += full11[yr][x0 + p + 10] - full11[yr][x0 + p + 4];
            gy1 += top6[yr][x0 + p + 10]   - top6[yr][x0 + p - 1];
            gy2 += bot6[yr][x0 + p + 10]   - bot6[yr][x0 + p - 1];
            float lx = __logf(gx1) - __logf(gx2);
            float ly = __logf(gy1) - __logf(gy2);
            float v = sqrtf(lx * lx + ly * ly);
            if (p == 1) res.y = v; else if (p == 2) res.z = v; else res.w = v;
        }
        *(float4*)&outb[(size_t)(Y0 + yr) * N + X0 + x0] = res;
    }
}

extern "C" void kernel_launch(void* const* d_in, const int* in_sizes, int n_in,
                              void* d_out, int out_size, void* d_ws, size_t ws_size,
                              hipStream_t stream) {
    const float* x = (const float*)d_in[0];  // (64,1,512,512) fp32
    float* out = (float*)d_out;              // (64,1,512,512) fp32
    dim3 grid(N / TW, N / TH, 64);
    dim3 block(256);
    boxlog_kernel<<<grid, block, 0, stream>>>(x, out);
}

// Round 2
// 89.421 us; speedup vs baseline: 1.1722x; 1.1722x over previous
//
#include <hip/hip_runtime.h>

// Box-log-edge: 4 half-box 11x11 sums via separable column sums.
// Phase A (160 thr): global float4 loads -> register column sums (top6/bot6/full11)
//   for 4 output rows each, written to LDS as float4 (stride 84, conflict-free).
// Phase B (256 thr): 18x ds_read_b128 -> full register sliding window over 8 px,
//   log-ratio + L2 norm, float4 stores.

#define N   512
#define TW  64
#define TH  32
#define SS  84   // sum-array stride in floats (mult of 4 for b128, 84%32=20 -> conflict-free)

__device__ __forceinline__ float4 f4add(float4 a, float4 b){ return make_float4(a.x+b.x,a.y+b.y,a.z+b.z,a.w+b.w); }
__device__ __forceinline__ float4 f4sub(float4 a, float4 b){ return make_float4(a.x-b.x,a.y-b.y,a.z-b.z,a.w-b.w); }
__device__ __forceinline__ float4 f4addc(float4 a, float c){ return make_float4(a.x+c,a.y+c,a.z+c,a.w+c); }

__global__ __launch_bounds__(256) void boxlog_kernel(
    const float* __restrict__ x, float* __restrict__ out)
{
    __shared__ __align__(16) float fullA[TH*SS];
    __shared__ __align__(16) float topA [TH*SS];
    __shared__ __align__(16) float botA [TH*SS];

    const int tid = threadIdx.x;
    // XCD-aware swizzle: each XCD gets 8 contiguous images (halo L2 locality)
    const int wg  = blockIdx.x;
    const int sw  = (wg & 7) * 1024 + (wg >> 3);
    const int bz  = sw >> 7;          // image 0..63
    const int rem = sw & 127;
    const int by  = rem >> 3;         // 0..15
    const int bx  = rem & 7;          // 0..7
    const int X0 = bx * TW, Y0 = by * TH;
    const float* __restrict__ xb   = x   + (size_t)bz * ((size_t)N * N);
    float* __restrict__       outb = out + (size_t)bz * ((size_t)N * N);

    // ---------------- Phase A: column sums ----------------
    // 160 threads: 20 col-chunks (4 cols each, c' = 4ch..4ch+3 <-> global X0-8+c')
    //            x 8 row-groups (4 output rows each)
    if (tid < 160) {
        const int rg = tid / 20;          // 0..7
        const int ch = tid - rg * 20;     // 0..19
        const int r0 = rg * 4;
        const int gc = X0 - 8 + ch * 4;
        const bool vec = (gc >= 0) && (gc <= N - 4);
        float4 t[14];
        #pragma unroll
        for (int j = 0; j < 14; ++j) {
            int gr = Y0 - 5 + r0 + j;
            gr = gr < 0 ? -gr : (gr > N-1 ? 2*(N-1) - gr : gr);
            const float* rowp = xb + (size_t)gr * N;
            if (vec) {
                t[j] = *(const float4*)(rowp + gc);
            } else {
                float v[4];
                #pragma unroll
                for (int i = 0; i < 4; ++i) {
                    int c = gc + i;
                    c = c < 0 ? -c : (c > N-1 ? 2*(N-1) - c : c);
                    v[i] = rowp[c];
                }
                t[j] = make_float4(v[0], v[1], v[2], v[3]);
            }
        }
        // output row r0+k needs padded rows (r0+k)..(r0+k+10) = t[k..k+10]
        float4 tp = f4add(f4add(f4add(t[0],t[1]),f4add(t[2],t[3])),f4add(t[4],t[5]));
        float4 bt = f4add(f4add(f4add(t[5],t[6]),f4add(t[7],t[8])),f4add(t[9],t[10]));
        #pragma unroll
        for (int k = 0; k < 4; ++k) {
            if (k) {
                tp = f4sub(f4add(tp, t[k+5]),  t[k-1]);
                bt = f4sub(f4add(bt, t[k+10]), t[k+4]);
            }
            float4 fu = f4sub(f4add(tp, bt), t[k+5]);
            const int b = (r0 + k) * SS + ch * 4;
            // fold the reference's +0.01 shift into the sums (6*0.01 / 11*0.01)
            *(float4*)&topA [b] = f4addc(tp, 0.06f);
            *(float4*)&botA [b] = f4addc(bt, 0.06f);
            *(float4*)&fullA[b] = f4addc(fu, 0.11f);
        }
    }
    __syncthreads();

    // ---------------- Phase B: horizontal sliding window, 8 px/thread --------
    const int tx = tid & 7;       // 8 strips of 8 px
    const int ty = tid >> 3;      // 32 rows
    const int base = ty * SS + tx * 8;

    float f[24], t6[24], b6[24];
    #pragma unroll
    for (int i = 0; i < 6; ++i) {
        *(float4*)&f [4*i] = *(const float4*)&fullA[base + 4*i];
        *(float4*)&t6[4*i] = *(const float4*)&topA [base + 4*i];
        *(float4*)&b6[4*i] = *(const float4*)&botA [base + 4*i];
    }
    // output col o = 8*tx + p ; window c' = o+3+kx -> local idx p+3+kx
    float gx1 = ((f[3]+f[4])+(f[5]+f[6]))+(f[7]+f[8]);
    float gx2 = ((f[8]+f[9])+(f[10]+f[11]))+(f[12]+f[13]);
    float gy1 = (((t6[3]+t6[4])+(t6[5]+t6[6]))+((t6[7]+t6[8])+(t6[9]+t6[10])))+((t6[11]+t6[12])+t6[13]);
    float gy2 = (((b6[3]+b6[4])+(b6[5]+b6[6]))+((b6[7]+b6[8])+(b6[9]+b6[10])))+((b6[11]+b6[12])+b6[13]);

    float r8[8];
    #pragma unroll
    for (int p = 0; p < 8; ++p) {
        if (p) {
            gx1 += f[p+8]   - f[p+2];
            gx2 += f[p+13]  - f[p+7];
            gy1 += t6[p+13] - t6[p+2];
            gy2 += b6[p+13] - b6[p+2];
        }
        float lx = __logf(gx1) - __logf(gx2);
        float ly = __logf(gy1) - __logf(gy2);
        r8[p] = sqrtf(lx*lx + ly*ly);
    }

    float* op = outb + (size_t)(Y0 + ty) * N + X0 + tx * 8;
    *(float4*)op       = make_float4(r8[0], r8[1], r8[2], r8[3]);
    *(float4*)(op + 4) = make_float4(r8[4], r8[5], r8[6], r8[7]);
}

extern "C" void kernel_launch(void* const* d_in, const int* in_sizes, int n_in,
                              void* d_out, int out_size, void* d_ws, size_t ws_size,
                              hipStream_t stream) {
    const float* x = (const float*)d_in[0];  // (64,1,512,512) fp32
    float* out = (float*)d_out;              // (64,1,512,512) fp32
    dim3 grid(8 * 16 * 64);                  // 1D, decoded+swizzled in-kernel
    dim3 block(256);
    boxlog_kernel<<<grid, block, 0, stream>>>(x, out);
}

// Round 3
// 61.122 us; speedup vs baseline: 1.7149x; 1.4630x over previous
//
#include <hip/hip_runtime.h>

// Box-log-edge: 4 half-box 11x11 sums via separable column sums.
// Phase A (160 thr): global float4 loads -> register column sums (top6/bot6/full11),
//   written to LDS as float4 (stride 84, conflict-free for b128).
// Phase B (256 thr): three low-liveness passes over topA/botA/fullA with
//   ds_read_b128, sliding windows in registers, log2-domain ratio + L2 norm.

#define N   512
#define TW  64
#define TH  32
#define SS  84   // stride in floats: mult of 4 (b128), 84%32=20 -> spread banks

#define LN2 0.69314718056f

__device__ __forceinline__ float4 f4add(float4 a, float4 b){ return make_float4(a.x+b.x,a.y+b.y,a.z+b.z,a.w+b.w); }
__device__ __forceinline__ float4 f4sub(float4 a, float4 b){ return make_float4(a.x-b.x,a.y-b.y,a.z-b.z,a.w-b.w); }
__device__ __forceinline__ float4 f4addc(float4 a, float c){ return make_float4(a.x+c,a.y+c,a.z+c,a.w+c); }

__global__ __launch_bounds__(256, 4) void boxlog_kernel(
    const float* __restrict__ x, float* __restrict__ out)
{
    __shared__ __align__(16) float fullA[TH*SS];
    __shared__ __align__(16) float topA [TH*SS];
    __shared__ __align__(16) float botA [TH*SS];

    const int tid = threadIdx.x;
    // XCD-aware swizzle: each XCD gets 8 contiguous images (halo L2 locality)
    const int wg  = blockIdx.x;
    const int sw  = (wg & 7) * 1024 + (wg >> 3);
    const int bz  = sw >> 7;          // image 0..63
    const int rem = sw & 127;
    const int by  = rem >> 3;         // 0..15
    const int bx  = rem & 7;          // 0..7
    const int X0 = bx * TW, Y0 = by * TH;
    const float* __restrict__ xb   = x   + (size_t)bz * ((size_t)N * N);
    float* __restrict__       outb = out + (size_t)bz * ((size_t)N * N);

    // ---------------- Phase A: column sums ----------------
    // 160 threads: 20 col-chunks (4 cols) x 8 row-groups (4 output rows)
    if (tid < 160) {
        const int rg = tid / 20;          // 0..7
        const int ch = tid - rg * 20;     // 0..19
        const int r0 = rg * 4;
        const int gc = X0 - 8 + ch * 4;
        float4 t[14];
        if (bx != 0 && bx != 7) {
            // interior block: every chunk is a clean vector load (uniform branch)
            #pragma unroll
            for (int j = 0; j < 14; ++j) {
                int gr = Y0 - 5 + r0 + j;
                gr = gr < 0 ? -gr : (gr > N-1 ? 2*(N-1) - gr : gr);
                t[j] = *(const float4*)(xb + (size_t)gr * N + gc);
            }
        } else {
            const bool vec = (gc >= 0) && (gc <= N - 4);
            #pragma unroll
            for (int j = 0; j < 14; ++j) {
                int gr = Y0 - 5 + r0 + j;
                gr = gr < 0 ? -gr : (gr > N-1 ? 2*(N-1) - gr : gr);
                const float* rowp = xb + (size_t)gr * N;
                if (vec) {
                    t[j] = *(const float4*)(rowp + gc);
                } else {
                    float v[4];
                    #pragma unroll
                    for (int i = 0; i < 4; ++i) {
                        int c = gc + i;
                        c = c < 0 ? -c : (c > N-1 ? 2*(N-1) - c : c);
                        v[i] = rowp[c];
                    }
                    t[j] = make_float4(v[0], v[1], v[2], v[3]);
                }
            }
        }
        // output row r0+k needs padded rows t[k..k+10]
        float4 tp = f4add(f4add(f4add(t[0],t[1]),f4add(t[2],t[3])),f4add(t[4],t[5]));
        float4 bt = f4add(f4add(f4add(t[5],t[6]),f4add(t[7],t[8])),f4add(t[9],t[10]));
        #pragma unroll
        for (int k = 0; k < 4; ++k) {
            if (k) {
                tp = f4sub(f4add(tp, t[k+5]),  t[k-1]);
                bt = f4sub(f4add(bt, t[k+10]), t[k+4]);
            }
            float4 fu = f4sub(f4add(tp, bt), t[k+5]);
            const int b = (r0 + k) * SS + ch * 4;
            // fold the reference's +0.01 shift into the sums
            *(float4*)&topA [b] = f4addc(tp, 0.06f);
            *(float4*)&botA [b] = f4addc(bt, 0.06f);
            *(float4*)&fullA[b] = f4addc(fu, 0.11f);
        }
    }
    __syncthreads();

    // ------------- Phase B: three low-liveness sliding-window passes ---------
    const int tx = tid & 7;       // 8 strips of 8 px
    const int ty = tid >> 3;      // 32 rows
    const int base = ty * SS + tx * 8;

    float acc[8];   // gy1 windows, then log2(gy1)-log2(gy2)

    {   // pass 1: top6 -> gy1 windows (11-wide)
        float t[24];
        #pragma unroll
        for (int i = 0; i < 6; ++i)
            *(float4*)&t[4*i] = *(const float4*)&topA[base + 4*i];
        float g = (((t[3]+t[4])+(t[5]+t[6]))+((t[7]+t[8])+(t[9]+t[10])))+((t[11]+t[12])+t[13]);
        acc[0] = g;
        #pragma unroll
        for (int p = 1; p < 8; ++p) { g += t[p+13] - t[p+2]; acc[p] = g; }
    }
    {   // pass 2: bot6 -> gy2 windows, fold into log2 ratio
        float t[24];
        #pragma unroll
        for (int i = 0; i < 6; ++i)
            *(float4*)&t[4*i] = *(const float4*)&botA[base + 4*i];
        float g = (((t[3]+t[4])+(t[5]+t[6]))+((t[7]+t[8])+(t[9]+t[10])))+((t[11]+t[12])+t[13]);
        acc[0] = __builtin_amdgcn_logf(acc[0]) - __builtin_amdgcn_logf(g);
        #pragma unroll
        for (int p = 1; p < 8; ++p) {
            g += t[p+13] - t[p+2];
            acc[p] = __builtin_amdgcn_logf(acc[p]) - __builtin_amdgcn_logf(g);
        }
    }
    {   // pass 3: full11 -> gx windows (6-wide pair), final combine + store
        float t[24];
        #pragma unroll
        for (int i = 0; i < 6; ++i)
            *(float4*)&t[4*i] = *(const float4*)&fullA[base + 4*i];
        float g1 = ((t[3]+t[4])+(t[5]+t[6]))+(t[7]+t[8]);
        float g2 = ((t[8]+t[9])+(t[10]+t[11]))+(t[12]+t[13]);
        float r8[8];
        #pragma unroll
        for (int p = 0; p < 8; ++p) {
            if (p) {
                g1 += t[p+8]  - t[p+2];
                g2 += t[p+13] - t[p+7];
            }
            float lx = __builtin_amdgcn_logf(g1) - __builtin_amdgcn_logf(g2);
            r8[p] = LN2 * __builtin_amdgcn_sqrtf(lx*lx + acc[p]*acc[p]);
        }
        float* op = outb + (size_t)(Y0 + ty) * N + X0 + tx * 8;
        *(float4*)op       = make_float4(r8[0], r8[1], r8[2], r8[3]);
        *(float4*)(op + 4) = make_float4(r8[4], r8[5], r8[6], r8[7]);
    }
}

extern "C" void kernel_launch(void* const* d_in, const int* in_sizes, int n_in,
                              void* d_out, int out_size, void* d_ws, size_t ws_size,
                              hipStream_t stream) {
    const float* x = (const float*)d_in[0];  // (64,1,512,512) fp32
    float* out = (float*)d_out;              // (64,1,512,512) fp32
    dim3 grid(8 * 16 * 64);                  // 1D, decoded+swizzled in-kernel
    dim3 block(256);
    boxlog_kernel<<<grid, block, 0, stream>>>(x, out);
}